// Round 6
// baseline (777.843 us; speedup 1.0000x reference)
//
#include <hip/hip_runtime.h>
#include <hip/hip_bf16.h>
#include <cstdint>

#define N_NODES 100000
#define N_EDGES 1600000
#define N_GRAPHS 2000
#define IN_DIM 37
#define HID 128

#define FILL_BLOCKS 6250   // 1.6M / 256
#define CONV_BLOCKS 6250   // 100k nodes * 16 quad-tasks / 256
#define PACK_BLOCKS 480    // (3*8192 + 6*16384) / 256
#define GEMM_GRID   1563   // (100000+63)/64

typedef __attribute__((ext_vector_type(8))) short short8;
typedef __attribute__((ext_vector_type(4))) float f32x4;

static __device__ __forceinline__ short bf16_bits(float f) {
    __hip_bfloat16 h = __float2bfloat16(f);
    return *reinterpret_cast<short*>(&h);
}
static __device__ __forceinline__ float bf16_lo(uint32_t u) {
    uint32_t v = u << 16;
    return *reinterpret_cast<float*>(&v);
}
static __device__ __forceinline__ float bf16_hi(uint32_t u) {
    uint32_t v = u & 0xffff0000u;
    return *reinterpret_cast<float*>(&v);
}

// ---------------- phase 1: hist(+rank) || x->bf16 convert || weight pack ----------------

struct PackArgs {
    const float* w[9];
    short* o[9];
};

__global__ __launch_bounds__(256) void fused_hist_conv_pack(const int* __restrict__ ei,
                                                            int* __restrict__ cnt,
                                                            int* __restrict__ rank,
                                                            const float* __restrict__ x,
                                                            short* __restrict__ Xb,
                                                            PackArgs pa) {
    const int b = blockIdx.x;
    const int tid = threadIdx.x;

    if (b < FILL_BLOCKS) {                       // hist + per-edge rank (ONLY atomic pass)
        const int e = b * 256 + tid;
        const int d = ei[N_EDGES + e];
        rank[e] = atomicAdd(&cnt[d], 1);
        return;
    }
    if (b < FILL_BLOCKS + CONV_BLOCKS) {         // x (fp32, 37) -> Xb (bf16, padded 64)
        const int idx = (b - FILL_BLOCKS) * 256 + tid;
        const int n = idx >> 4, j = idx & 15;
        const int k0 = j * 4;
        short4 o;
        o.x = (k0 + 0 < IN_DIM) ? bf16_bits(x[(size_t)n * IN_DIM + k0 + 0]) : (short)0;
        o.y = (k0 + 1 < IN_DIM) ? bf16_bits(x[(size_t)n * IN_DIM + k0 + 1]) : (short)0;
        o.z = (k0 + 2 < IN_DIM) ? bf16_bits(x[(size_t)n * IN_DIM + k0 + 2]) : (short)0;
        o.w = (k0 + 3 < IN_DIM) ? bf16_bits(x[(size_t)n * IN_DIM + k0 + 3]) : (short)0;
        *(short4*)(Xb + (size_t)n * 64 + k0) = o;
        return;
    }
    // pack: packed[kb*4096 + t*512 + lane*8 + i] = bf16(W[kb*32+(lane>>4)*8+i][t*16+(lane&15)])
    int idx = (b - FILL_BLOCKS - CONV_BLOCKS) * 256 + tid;
    int m, r, kin;
    if (idx < 24576) { m = idx >> 13; r = idx & 8191; kin = IN_DIM; }
    else { int q = idx - 24576; m = 3 + (q >> 14); r = q & 16383; kin = HID; }
    const int i = r & 7, lane = (r >> 3) & 63, t = (r >> 9) & 7, kb = r >> 12;
    const int k = kb * 32 + (lane >> 4) * 8 + i;
    const int c = t * 16 + (lane & 15);
    float v = (k < kin) ? pa.w[m][(size_t)k * HID + c] : 0.f;
    pa.o[m][r] = bf16_bits(v);
}

// ---------------- scan: cnt -> rowptr (+degf) ----------------

__global__ __launch_bounds__(1024) void scan_blocks(const int* __restrict__ cnt,
                                                    int* __restrict__ partial,
                                                    int* __restrict__ bsum) {
    __shared__ int ws[16];
    const int tid = threadIdx.x, lane = tid & 63, wv = tid >> 6;
    const int i = blockIdx.x * 1024 + tid;
    int v0 = (i < N_NODES) ? cnt[i] : 0;
    int v = v0;
    #pragma unroll
    for (int off = 1; off < 64; off <<= 1) {
        int n = __shfl_up(v, off, 64);
        if (lane >= off) v += n;
    }
    if (lane == 63) ws[wv] = v;
    __syncthreads();
    int woff = 0, tot = 0;
    #pragma unroll
    for (int w = 0; w < 16; w++) {
        int s = ws[w];
        if (w < wv) woff += s;
        tot += s;
    }
    if (i < N_NODES) partial[i] = woff + v - v0;
    if (tid == 0) bsum[blockIdx.x] = tot;
}

__global__ __launch_bounds__(1024) void scan_finalize(const int* __restrict__ partial,
                                                      const int* __restrict__ bsum,
                                                      const int* __restrict__ cnt,
                                                      int* __restrict__ rowptr,
                                                      float* __restrict__ degf) {
    __shared__ int off_s;
    const int tid = threadIdx.x, b = blockIdx.x;
    if (tid < 64) {
        int acc = 0;
        for (int j = tid; j < b; j += 64) acc += bsum[j];
        #pragma unroll
        for (int off = 32; off; off >>= 1) acc += __shfl_down(acc, off, 64);
        if (tid == 0) off_s = acc;
    }
    __syncthreads();
    const int i = b * 1024 + tid;
    if (i < N_NODES) {
        rowptr[i] = off_s + partial[i];
        degf[i] = (float)cnt[i];
    }
    if (b == 0 && tid == 0) rowptr[N_NODES] = N_EDGES;
}

// ---------------- LEConv GEMM body from GLOBAL activations (layer 0) ----------------
// OUT = deg*(h@W1 + b1) + h@W3 + b3 (fp32), B = h@W2 (bf16)

template <int K32>
static __device__ __forceinline__ void leconv_body(
    int blk,
    const short* __restrict__ Hb,
    const short* __restrict__ Wp1, const short* __restrict__ Wp2, const short* __restrict__ Wp3,
    const float* __restrict__ b1v, const float* __restrict__ b3v,
    const float* __restrict__ deg,
    short* __restrict__ Bb, float* __restrict__ OUT) {
    constexpr int K = K32 * 32;
    const int tid = threadIdx.x;
    const int wave = tid >> 6, lane = tid & 63;
    const int row_base = blk * 64 + wave * 16;
    const int r15 = lane & 15, kg = lane >> 4;

    int arow = row_base + r15;
    if (arow >= N_NODES) arow = N_NODES - 1;
    const short* aptr = Hb + (size_t)arow * K + kg * 8;

    f32x4 acc1[8], acc2[8], acc3[8];
    #pragma unroll
    for (int t = 0; t < 8; t++) {
        acc1[t] = (f32x4)0.f; acc2[t] = (f32x4)0.f; acc3[t] = (f32x4)0.f;
    }

    #pragma unroll
    for (int kb = 0; kb < K32; kb++) {
        short8 a = *(const short8*)(aptr + kb * 32);
        #pragma unroll
        for (int t = 0; t < 8; t++) {
            const int widx = (kb * 8 + t) * 512 + lane * 8;
            short8 w1 = *(const short8*)(Wp1 + widx);
            short8 w2 = *(const short8*)(Wp2 + widx);
            short8 w3 = *(const short8*)(Wp3 + widx);
            acc1[t] = __builtin_amdgcn_mfma_f32_16x16x32_bf16(a, w1, acc1[t], 0, 0, 0);
            acc2[t] = __builtin_amdgcn_mfma_f32_16x16x32_bf16(a, w2, acc2[t], 0, 0, 0);
            acc3[t] = __builtin_amdgcn_mfma_f32_16x16x32_bf16(a, w3, acc3[t], 0, 0, 0);
        }
    }

    int grow[4];
    bool ok[4];
    float dg[4];
    #pragma unroll
    for (int i = 0; i < 4; i++) {
        grow[i] = row_base + kg * 4 + i;
        ok[i] = grow[i] < N_NODES;
        dg[i] = ok[i] ? deg[grow[i]] : 0.f;
    }
    #pragma unroll
    for (int t = 0; t < 8; t++) {
        const int c = t * 16 + r15;
        const float bb1 = b1v[c], bb3 = b3v[c];
        #pragma unroll
        for (int i = 0; i < 4; i++) {
            if (ok[i]) {
                size_t o = (size_t)grow[i] * HID + c;
                OUT[o] = dg[i] * (acc1[t][i] + bb1) + acc3[t][i] + bb3;
                Bb[o] = bf16_bits(acc2[t][i]);
            }
        }
    }
}

// ---------------- phase 2: scatter col (no atomics) || layer-0 GEMM ----------------

__global__ __launch_bounds__(256) void fused_fill_gemm(
    const int* __restrict__ ei, const int* __restrict__ rank, const int* __restrict__ rowptr,
    int* __restrict__ col,
    const short* __restrict__ Xb,
    const short* __restrict__ Wp1, const short* __restrict__ Wp2, const short* __restrict__ Wp3,
    const float* __restrict__ b1v, const float* __restrict__ b3v,
    const float* __restrict__ deg,
    short* __restrict__ Bb, float* __restrict__ OUT) {
    const int b = blockIdx.x;
    if (b < FILL_BLOCKS) {
        const int e = b * 256 + threadIdx.x;
        const int s = ei[e];
        const int d = ei[N_EDGES + e];
        col[rowptr[d] + rank[e]] = s;
        return;
    }
    leconv_body<2>(b - FILL_BLOCKS, Xb, Wp1, Wp2, Wp3, b1v, b3v, deg, Bb, OUT);
}

// ---------------- fused gather + next-layer GEMM ----------------
// Per wave: gather+relu its 16 node rows (prev layer) -> wave-private LDS tile,
// then MFMA GEMM (K=128) from LDS. No barrier needed (wave-private LDS).
// Reads OUT_prev/Bb_prev, writes OUT_out/Bb_out (double-buffered vs prev).

__global__ __launch_bounds__(256) void gather_gemm(
    const int* __restrict__ rowptr, const int* __restrict__ col,
    const short* __restrict__ Bb_prev, const float* __restrict__ OUT_prev,
    const short* __restrict__ Wp1, const short* __restrict__ Wp2, const short* __restrict__ Wp3,
    const float* __restrict__ b1v, const float* __restrict__ b3v,
    const float* __restrict__ deg,
    short* __restrict__ Bb_out, float* __restrict__ OUT_out) {
    __shared__ short hs[4][16][136];  // stride 136 shorts = 68 dwords -> 2-way bank alias (free)

    const int tid = threadIdx.x;
    const int wave = tid >> 6, lane = tid & 63;
    const int row_base = blockIdx.x * 64 + wave * 16;

    // ---- gather phase: this wave's 16 rows ----
    for (int r = 0; r < 16; r++) {
        int node = row_base + r;
        int nc = (node < N_NODES) ? node : N_NODES - 1;
        const int s = rowptr[nc], e = rowptr[nc + 1];
        float ax0 = 0.f, ay0 = 0.f, ax1 = 0.f, ay1 = 0.f;
        int t = s;
        for (; t + 4 <= e; t += 4) {
            const int c0 = col[t], c1 = col[t + 1], c2 = col[t + 2], c3 = col[t + 3];
            const uint32_t u0 = *(const uint32_t*)(Bb_prev + (size_t)c0 * HID + lane * 2);
            const uint32_t u1 = *(const uint32_t*)(Bb_prev + (size_t)c1 * HID + lane * 2);
            const uint32_t u2 = *(const uint32_t*)(Bb_prev + (size_t)c2 * HID + lane * 2);
            const uint32_t u3 = *(const uint32_t*)(Bb_prev + (size_t)c3 * HID + lane * 2);
            ax0 += bf16_lo(u0) + bf16_lo(u2);
            ay0 += bf16_hi(u0) + bf16_hi(u2);
            ax1 += bf16_lo(u1) + bf16_lo(u3);
            ay1 += bf16_hi(u1) + bf16_hi(u3);
        }
        for (; t < e; t++) {
            const int c0 = col[t];
            const uint32_t u0 = *(const uint32_t*)(Bb_prev + (size_t)c0 * HID + lane * 2);
            ax0 += bf16_lo(u0);
            ay0 += bf16_hi(u0);
        }
        const float2 o = *(const float2*)(OUT_prev + (size_t)nc * HID + lane * 2);
        const float ox = fmaxf(o.x - (ax0 + ax1), 0.f);
        const float oy = fmaxf(o.y - (ay0 + ay1), 0.f);
        const uint32_t pk = ((uint32_t)(uint16_t)bf16_bits(oy) << 16) | (uint16_t)bf16_bits(ox);
        *(uint32_t*)&hs[wave][r][lane * 2] = pk;
    }

    // ---- GEMM phase (K = 128) from wave-private LDS ----
    const int r15 = lane & 15, kg = lane >> 4;
    const short* aptr = &hs[wave][r15][kg * 8];

    f32x4 acc1[8], acc2[8], acc3[8];
    #pragma unroll
    for (int t = 0; t < 8; t++) {
        acc1[t] = (f32x4)0.f; acc2[t] = (f32x4)0.f; acc3[t] = (f32x4)0.f;
    }

    #pragma unroll
    for (int kb = 0; kb < 4; kb++) {
        short8 a = *(const short8*)(aptr + kb * 32);
        #pragma unroll
        for (int t = 0; t < 8; t++) {
            const int widx = (kb * 8 + t) * 512 + lane * 8;
            short8 w1 = *(const short8*)(Wp1 + widx);
            short8 w2 = *(const short8*)(Wp2 + widx);
            short8 w3 = *(const short8*)(Wp3 + widx);
            acc1[t] = __builtin_amdgcn_mfma_f32_16x16x32_bf16(a, w1, acc1[t], 0, 0, 0);
            acc2[t] = __builtin_amdgcn_mfma_f32_16x16x32_bf16(a, w2, acc2[t], 0, 0, 0);
            acc3[t] = __builtin_amdgcn_mfma_f32_16x16x32_bf16(a, w3, acc3[t], 0, 0, 0);
        }
    }

    int grow[4];
    bool ok[4];
    float dg[4];
    #pragma unroll
    for (int i = 0; i < 4; i++) {
        grow[i] = row_base + kg * 4 + i;
        ok[i] = grow[i] < N_NODES;
        dg[i] = ok[i] ? deg[grow[i]] : 0.f;
    }
    #pragma unroll
    for (int t = 0; t < 8; t++) {
        const int c = t * 16 + r15;
        const float bb1 = b1v[c], bb3 = b3v[c];
        #pragma unroll
        for (int i = 0; i < 4; i++) {
            if (ok[i]) {
                size_t o = (size_t)grow[i] * HID + c;
                OUT_out[o] = dg[i] * (acc1[t][i] + bb1) + acc3[t][i] + bb3;
                Bb_out[o] = bf16_bits(acc2[t][i]);
            }
        }
    }
}

// ---------------- final gather: Hb = bf16(relu(OUT - agg)) ----------------

__global__ __launch_bounds__(256) void gather_csr(const int* __restrict__ rowptr,
                                                  const int* __restrict__ col,
                                                  const short* __restrict__ Bb,
                                                  const float* __restrict__ OUT,
                                                  short* __restrict__ Hb) {
    const int wid = (blockIdx.x * 256 + threadIdx.x) >> 6;
    const int lane = threadIdx.x & 63;
    if (wid >= N_NODES) return;
    const int s = rowptr[wid], e = rowptr[wid + 1];
    float ax0 = 0.f, ay0 = 0.f, ax1 = 0.f, ay1 = 0.f;
    int t = s;
    for (; t + 4 <= e; t += 4) {
        const int c0 = col[t], c1 = col[t + 1], c2 = col[t + 2], c3 = col[t + 3];
        const uint32_t u0 = *(const uint32_t*)(Bb + (size_t)c0 * HID + lane * 2);
        const uint32_t u1 = *(const uint32_t*)(Bb + (size_t)c1 * HID + lane * 2);
        const uint32_t u2 = *(const uint32_t*)(Bb + (size_t)c2 * HID + lane * 2);
        const uint32_t u3 = *(const uint32_t*)(Bb + (size_t)c3 * HID + lane * 2);
        ax0 += bf16_lo(u0) + bf16_lo(u2);
        ay0 += bf16_hi(u0) + bf16_hi(u2);
        ax1 += bf16_lo(u1) + bf16_lo(u3);
        ay1 += bf16_hi(u1) + bf16_hi(u3);
    }
    for (; t < e; t++) {
        const int c0 = col[t];
        const uint32_t u0 = *(const uint32_t*)(Bb + (size_t)c0 * HID + lane * 2);
        ax0 += bf16_lo(u0);
        ay0 += bf16_hi(u0);
    }
    const float ax = ax0 + ax1, ay = ay0 + ay1;
    const float2 o = *(const float2*)(OUT + (size_t)wid * HID + lane * 2);
    const float ox = fmaxf(o.x - ax, 0.f);
    const float oy = fmaxf(o.y - ay, 0.f);
    const uint32_t r = ((uint32_t)(uint16_t)bf16_bits(oy) << 16) | (uint16_t)bf16_bits(ox);
    *(uint32_t*)(Hb + (size_t)wid * HID + lane * 2) = r;
}

// ---------------- pool (mean of bf16 H) + FFN head ----------------

__global__ __launch_bounds__(128) void pool_ffn_kernel(const short* __restrict__ H,
                                                       const int* __restrict__ batch,
                                                       const float* __restrict__ Wf1,
                                                       const float* __restrict__ bf1,
                                                       const float* __restrict__ Wf2,
                                                       const float* __restrict__ bf2,
                                                       float* __restrict__ out) {
    const int g = blockIdx.x;
    const int t = threadIdx.x;  // 0..127

    int lo = 0, hi = N_NODES;
    while (lo < hi) { int mid = (lo + hi) >> 1; if (batch[mid] < g) lo = mid + 1; else hi = mid; }
    const int s = lo;
    hi = N_NODES;
    while (lo < hi) { int mid = (lo + hi) >> 1; if (batch[mid] < g + 1) lo = mid + 1; else hi = mid; }
    const int e = lo;

    float sum = 0.f;
    for (int n = s; n < e; n++) {
        short b = H[(size_t)n * HID + t];
        sum += __bfloat162float(*(__hip_bfloat16*)&b);
    }
    const float cntf = (float)(e - s);
    const float gx = sum / fmaxf(cntf, 1.f);

    __shared__ float lds[HID];
    lds[t] = gx;
    __syncthreads();

    float hsum = bf1[t];
    #pragma unroll 8
    for (int k = 0; k < HID; k++) hsum = fmaf(lds[k], Wf1[k * HID + t], hsum);
    const float hr = fmaxf(hsum, 0.f);

    float p0 = hr * Wf2[t * 2 + 0];
    float p1 = hr * Wf2[t * 2 + 1];
    #pragma unroll
    for (int off = 32; off > 0; off >>= 1) {
        p0 += __shfl_down(p0, off, 64);
        p1 += __shfl_down(p1, off, 64);
    }
    __shared__ float red[4];
    if ((t & 63) == 0) {
        red[(t >> 6) * 2 + 0] = p0;
        red[(t >> 6) * 2 + 1] = p1;
    }
    __syncthreads();
    if (t == 0) {
        out[g * 2 + 0] = red[0] + red[2] + bf2[0];
        out[g * 2 + 1] = red[1] + red[3] + bf2[1];
    }
}

// ---------------- launch ----------------

extern "C" void kernel_launch(void* const* d_in, const int* in_sizes, int n_in,
                              void* d_out, int out_size, void* d_ws, size_t ws_size,
                              hipStream_t stream) {
    (void)in_sizes; (void)n_in; (void)out_size; (void)ws_size;

    const float* x     = (const float*)d_in[0];
    const int*   ei    = (const int*)d_in[1];
    const int*   batch = (const int*)d_in[2];
    const float* W[9] = {
        (const float*)d_in[3],  (const float*)d_in[5],  (const float*)d_in[6],
        (const float*)d_in[8],  (const float*)d_in[10], (const float*)d_in[11],
        (const float*)d_in[13], (const float*)d_in[15], (const float*)d_in[16]};
    const float* b1_0 = (const float*)d_in[4];
    const float* b3_0 = (const float*)d_in[7];
    const float* b1_1 = (const float*)d_in[9];
    const float* b3_1 = (const float*)d_in[12];
    const float* b1_2 = (const float*)d_in[14];
    const float* b3_2 = (const float*)d_in[17];
    const float* Wf1  = (const float*)d_in[18];
    const float* bf1  = (const float*)d_in[19];
    const float* Wf2  = (const float*)d_in[20];
    const float* bf2  = (const float*)d_in[21];
    float* out = (float*)d_out;

    char* ws = (char*)d_ws;
    size_t off = 0;
    auto alloc = [&](size_t bytes) {
        void* p = ws + off;
        off += (bytes + 255) & ~(size_t)255;
        return p;
    };
    float* OUT_A  = (float*)alloc((size_t)N_NODES * HID * 4);
    float* OUT_B  = (float*)alloc((size_t)N_NODES * HID * 4);
    short* Bb_A   = (short*)alloc((size_t)N_NODES * HID * 2);
    short* Bb_B   = (short*)alloc((size_t)N_NODES * HID * 2);
    short* Hb     = (short*)alloc((size_t)N_NODES * HID * 2);
    short* Xb     = (short*)alloc((size_t)N_NODES * 64 * 2);
    float* degf   = (float*)alloc((size_t)N_NODES * 4);
    int*   rowptr = (int*)alloc((size_t)(N_NODES + 1) * 4);
    int*   cnt    = (int*)alloc((size_t)N_NODES * 4);
    int*   col    = (int*)alloc((size_t)N_EDGES * 4);
    int*   rank   = (int*)alloc((size_t)N_EDGES * 4);
    int*   partial= (int*)alloc((size_t)N_NODES * 4);
    int*   bsum   = (int*)alloc(1024);
    short* P[9];
    for (int m = 0; m < 9; m++) P[m] = (short*)alloc(16384 * 2);

    hipMemsetAsync(cnt, 0, (size_t)N_NODES * 4, stream);

    PackArgs pa;
    for (int m = 0; m < 9; m++) { pa.w[m] = W[m]; pa.o[m] = P[m]; }

    // phase 1: hist(+rank) || x convert || weight pack
    fused_hist_conv_pack<<<FILL_BLOCKS + CONV_BLOCKS + PACK_BLOCKS, 256, 0, stream>>>(
        ei, cnt, rank, x, Xb, pa);

    // scan
    const int NSB = (N_NODES + 1023) / 1024;  // 98
    scan_blocks<<<NSB, 1024, 0, stream>>>(cnt, partial, bsum);
    scan_finalize<<<NSB, 1024, 0, stream>>>(partial, bsum, cnt, rowptr, degf);

    // phase 2: scatter col (no atomics) || layer-0 GEMM  -> OUT_A, Bb_A
    fused_fill_gemm<<<FILL_BLOCKS + GEMM_GRID, 256, 0, stream>>>(
        ei, rank, rowptr, col, Xb, P[0], P[1], P[2], b1_0, b3_0, degf, Bb_A, OUT_A);

    // layer 1: gather(A) + gemm -> OUT_B, Bb_B
    gather_gemm<<<GEMM_GRID, 256, 0, stream>>>(
        rowptr, col, Bb_A, OUT_A, P[3], P[4], P[5], b1_1, b3_1, degf, Bb_B, OUT_B);

    // layer 2: gather(B) + gemm -> OUT_A, Bb_A
    gather_gemm<<<GEMM_GRID, 256, 0, stream>>>(
        rowptr, col, Bb_B, OUT_B, P[6], P[7], P[8], b1_2, b3_2, degf, Bb_A, OUT_A);

    // final gather -> Hb
    const int gather_grid = (N_NODES * 64 + 255) / 256;  // 25000
    gather_csr<<<gather_grid, 256, 0, stream>>>(rowptr, col, Bb_A, OUT_A, Hb);

    // pool + FFN
    pool_ffn_kernel<<<N_GRAPHS, 128, 0, stream>>>(Hb, batch, Wf1, bf1, Wf2, bf2, out);
}

// Round 8
// 526.542 us; speedup vs baseline: 1.4773x; 1.4773x over previous
//
#include <hip/hip_runtime.h>
#include <hip/hip_bf16.h>
#include <cstdint>

#define N_NODES 100000
#define N_EDGES 1600000
#define N_GRAPHS 2000
#define IN_DIM 37
#define HID 128

#define GEMM_GRID 1563      // 64-node tiles
#define HIST_BLOCKS 6250    // 1.6M / 256
#define PACK67_BLOCKS 384   // 6*16384/256 (m=3..8)
#define PREPACK_BLOCKS 96   // 3*8192/256  (m=0..2)

typedef __attribute__((ext_vector_type(8))) short short8;
typedef __attribute__((ext_vector_type(4))) float f32x4;

static __device__ __forceinline__ short bf16_bits(float f) {
    __hip_bfloat16 h = __float2bfloat16(f);
    return *reinterpret_cast<short*>(&h);
}
static __device__ __forceinline__ float bf16_lo(uint32_t u) {
    uint32_t v = u << 16;
    return *reinterpret_cast<float*>(&v);
}
static __device__ __forceinline__ float bf16_hi(uint32_t u) {
    uint32_t v = u & 0xffff0000u;
    return *reinterpret_cast<float*>(&v);
}

// ---------------- weight pack ----------------

struct PackArgs {
    const float* w[9];
    short* o[9];
};

static __device__ __forceinline__ void pack_one(const PackArgs& pa, int m, int r, int kin) {
    const int i = r & 7, lane = (r >> 3) & 63, t = (r >> 9) & 7, kb = r >> 12;
    const int k = kb * 32 + (lane >> 4) * 8 + i;
    const int c = t * 16 + (lane & 15);
    float v = (k < kin) ? pa.w[m][(size_t)k * HID + c] : 0.f;
    pa.o[m][r] = bf16_bits(v);
}

__global__ __launch_bounds__(256) void prepack_kernel(PackArgs pa) {
    const int idx = blockIdx.x * 256 + threadIdx.x;  // < 24576
    pack_one(pa, idx >> 13, idx & 8191, IN_DIM);
}

// ---------------- layer-0 GEMM from fp32 x (K=64 padded) ----------------
// D0 = bf16(x@W1 + b1), E0 = bf16(x@W3 + b3), Bb = bf16(x@W2)

static __device__ __forceinline__ void gemm0_body(
    int blk, const float* __restrict__ x,
    const short* __restrict__ Wp1, const short* __restrict__ Wp2, const short* __restrict__ Wp3,
    const float* __restrict__ b1v, const float* __restrict__ b3v,
    short* __restrict__ D0, short* __restrict__ E0, short* __restrict__ Bb) {
    const int tid = threadIdx.x;
    const int wave = tid >> 6, lane = tid & 63;
    const int row_base = blk * 64 + wave * 16;
    const int r15 = lane & 15, kg = lane >> 4;
    int arow = row_base + r15;
    if (arow >= N_NODES) arow = N_NODES - 1;
    const float* xr = x + (size_t)arow * IN_DIM;

    f32x4 acc1[8], acc2[8], acc3[8];
    #pragma unroll
    for (int t = 0; t < 8; t++) {
        acc1[t] = (f32x4)0.f; acc2[t] = (f32x4)0.f; acc3[t] = (f32x4)0.f;
    }
    #pragma unroll
    for (int kb = 0; kb < 2; kb++) {
        short8 av;
        #pragma unroll
        for (int i = 0; i < 8; i++) {
            const int k = kb * 32 + kg * 8 + i;
            av[i] = (k < IN_DIM) ? bf16_bits(xr[k]) : (short)0;
        }
        #pragma unroll
        for (int t = 0; t < 8; t++) {
            const int widx = (kb * 8 + t) * 512 + lane * 8;
            short8 w1 = *(const short8*)(Wp1 + widx);
            short8 w2 = *(const short8*)(Wp2 + widx);
            short8 w3 = *(const short8*)(Wp3 + widx);
            acc1[t] = __builtin_amdgcn_mfma_f32_16x16x32_bf16(av, w1, acc1[t], 0, 0, 0);
            acc2[t] = __builtin_amdgcn_mfma_f32_16x16x32_bf16(av, w2, acc2[t], 0, 0, 0);
            acc3[t] = __builtin_amdgcn_mfma_f32_16x16x32_bf16(av, w3, acc3[t], 0, 0, 0);
        }
    }
    int grow[4]; bool ok[4];
    #pragma unroll
    for (int i = 0; i < 4; i++) {
        grow[i] = row_base + kg * 4 + i;
        ok[i] = grow[i] < N_NODES;
    }
    #pragma unroll
    for (int t = 0; t < 8; t++) {
        const int c = t * 16 + r15;
        const float bb1 = b1v[c], bb3 = b3v[c];
        #pragma unroll
        for (int i = 0; i < 4; i++) {
            if (ok[i]) {
                size_t o = (size_t)grow[i] * HID + c;
                D0[o] = bf16_bits(acc1[t][i] + bb1);
                E0[o] = bf16_bits(acc3[t][i] + bb3);
                Bb[o] = bf16_bits(acc2[t][i]);
            }
        }
    }
}

// ---------------- phase 1: gemm0 || hist(+rank, only atomic pass) || pack m3..8 ----------------

struct P1Args {
    const float* x;
    const int* ei;
    int* cnt; int* rank;
    const short* Wp1; const short* Wp2; const short* Wp3;
    const float* b1; const float* b3;
    short* D0; short* E0; short* Bb;
    PackArgs pa;
};

__global__ __launch_bounds__(256) void phase1_kernel(P1Args a) {
    const int b = blockIdx.x;
    if (b < GEMM_GRID) {
        gemm0_body(b, a.x, a.Wp1, a.Wp2, a.Wp3, a.b1, a.b3, a.D0, a.E0, a.Bb);
        return;
    }
    if (b < GEMM_GRID + HIST_BLOCKS) {
        const int e = (b - GEMM_GRID) * 256 + threadIdx.x;
        const int d = a.ei[N_EDGES + e];
        a.rank[e] = atomicAdd(&a.cnt[d], 1);
        return;
    }
    const int idx = (b - GEMM_GRID - HIST_BLOCKS) * 256 + threadIdx.x;  // < 98304
    pack_one(a.pa, 3 + (idx >> 14), idx & 16383, HID);
}

// ---------------- scan: cnt -> rowptr (+degf) ----------------

__global__ __launch_bounds__(1024) void scan_blocks(const int* __restrict__ cnt,
                                                    int* __restrict__ partial,
                                                    int* __restrict__ bsum) {
    __shared__ int ws[16];
    const int tid = threadIdx.x, lane = tid & 63, wv = tid >> 6;
    const int i = blockIdx.x * 1024 + tid;
    int v0 = (i < N_NODES) ? cnt[i] : 0;
    int v = v0;
    #pragma unroll
    for (int off = 1; off < 64; off <<= 1) {
        int n = __shfl_up(v, off, 64);
        if (lane >= off) v += n;
    }
    if (lane == 63) ws[wv] = v;
    __syncthreads();
    int woff = 0, tot = 0;
    #pragma unroll
    for (int w = 0; w < 16; w++) {
        int s = ws[w];
        if (w < wv) woff += s;
        tot += s;
    }
    if (i < N_NODES) partial[i] = woff + v - v0;
    if (tid == 0) bsum[blockIdx.x] = tot;
}

__global__ __launch_bounds__(1024) void scan_finalize(const int* __restrict__ partial,
                                                      const int* __restrict__ bsum,
                                                      const int* __restrict__ cnt,
                                                      int* __restrict__ rowptr,
                                                      float* __restrict__ degf) {
    __shared__ int off_s;
    const int tid = threadIdx.x, b = blockIdx.x;
    if (tid < 64) {
        int acc = 0;
        for (int j = tid; j < b; j += 64) acc += bsum[j];
        #pragma unroll
        for (int off = 32; off; off >>= 1) acc += __shfl_down(acc, off, 64);
        if (tid == 0) off_s = acc;
    }
    __syncthreads();
    const int i = b * 1024 + tid;
    if (i < N_NODES) {
        rowptr[i] = off_s + partial[i];
        degf[i] = (float)cnt[i];
    }
    if (b == 0 && tid == 0) rowptr[N_NODES] = N_EDGES;
}

// ---------------- fill: scatter col (no atomics) ----------------

__global__ __launch_bounds__(256) void fill_kernel(const int* __restrict__ ei,
                                                   const int* __restrict__ rank,
                                                   const int* __restrict__ rowptr,
                                                   int* __restrict__ col) {
    const int e = blockIdx.x * 256 + threadIdx.x;
    const int s = ei[e];
    const int d = ei[N_EDGES + e];
    col[rowptr[d] + rank[e]] = s;
}

// ---------------- gather helpers ----------------

static __device__ __forceinline__ void agg_edges(const int* __restrict__ col, int s, int e,
                                                 const short* __restrict__ Bb, int lane2,
                                                 float& AX, float& AY) {
    float ax0 = 0.f, ay0 = 0.f, ax1 = 0.f, ay1 = 0.f;
    int t = s;
    for (; t < e && (t & 3); t++) {
        const uint32_t u = *(const uint32_t*)(Bb + (size_t)col[t] * HID + lane2);
        ax0 += bf16_lo(u); ay0 += bf16_hi(u);
    }
    for (; t + 4 <= e; t += 4) {
        const int4 c4 = *(const int4*)(col + t);
        const uint32_t u0 = *(const uint32_t*)(Bb + (size_t)c4.x * HID + lane2);
        const uint32_t u1 = *(const uint32_t*)(Bb + (size_t)c4.y * HID + lane2);
        const uint32_t u2 = *(const uint32_t*)(Bb + (size_t)c4.z * HID + lane2);
        const uint32_t u3 = *(const uint32_t*)(Bb + (size_t)c4.w * HID + lane2);
        ax0 += bf16_lo(u0) + bf16_lo(u2);
        ay0 += bf16_hi(u0) + bf16_hi(u2);
        ax1 += bf16_lo(u1) + bf16_lo(u3);
        ay1 += bf16_hi(u1) + bf16_hi(u3);
    }
    for (; t < e; t++) {
        const uint32_t u = *(const uint32_t*)(Bb + (size_t)col[t] * HID + lane2);
        ax0 += bf16_lo(u); ay0 += bf16_hi(u);
    }
    AX = ax0 + ax1; AY = ay0 + ay1;
}

// layer-0 gather: Hb = bf16(relu(deg*D0 - agg + E0)), deg from rowptr
__global__ __launch_bounds__(256) void gather0_kernel(const int* __restrict__ rowptr,
                                                      const int* __restrict__ col,
                                                      const short* __restrict__ Bb,
                                                      const short* __restrict__ D0,
                                                      const short* __restrict__ E0,
                                                      short* __restrict__ Hb) {
    const int wid = (blockIdx.x * 256 + threadIdx.x) >> 6;
    const int lane2 = (threadIdx.x & 63) * 2;
    if (wid >= N_NODES) return;
    const int s = rowptr[wid], e = rowptr[wid + 1];
    float ax, ay;
    agg_edges(col, s, e, Bb, lane2, ax, ay);
    const float dg = (float)(e - s);
    const uint32_t ud = *(const uint32_t*)(D0 + (size_t)wid * HID + lane2);
    const uint32_t ue = *(const uint32_t*)(E0 + (size_t)wid * HID + lane2);
    const float ox = fmaxf(fmaf(dg, bf16_lo(ud), bf16_lo(ue)) - ax, 0.f);
    const float oy = fmaxf(fmaf(dg, bf16_hi(ud), bf16_hi(ue)) - ay, 0.f);
    *(uint32_t*)(Hb + (size_t)wid * HID + lane2) =
        ((uint32_t)(uint16_t)bf16_bits(oy) << 16) | (uint16_t)bf16_bits(ox);
}

// layers 1/2 gather: Hb = bf16(relu(OUT - agg)), OUT bf16 (deg applied in gemm)
__global__ __launch_bounds__(256) void gatherL_kernel(const int* __restrict__ rowptr,
                                                      const int* __restrict__ col,
                                                      const short* __restrict__ Bb,
                                                      const short* __restrict__ OUTb,
                                                      short* __restrict__ Hb) {
    const int wid = (blockIdx.x * 256 + threadIdx.x) >> 6;
    const int lane2 = (threadIdx.x & 63) * 2;
    if (wid >= N_NODES) return;
    const int s = rowptr[wid], e = rowptr[wid + 1];
    float ax, ay;
    agg_edges(col, s, e, Bb, lane2, ax, ay);
    const uint32_t uo = *(const uint32_t*)(OUTb + (size_t)wid * HID + lane2);
    const float ox = fmaxf(bf16_lo(uo) - ax, 0.f);
    const float oy = fmaxf(bf16_hi(uo) - ay, 0.f);
    *(uint32_t*)(Hb + (size_t)wid * HID + lane2) =
        ((uint32_t)(uint16_t)bf16_bits(oy) << 16) | (uint16_t)bf16_bits(ox);
}

// ---------------- layers 1/2 GEMM: OUT = bf16(deg*(h@W1+b1)+h@W3+b3), Bb = bf16(h@W2) ----------------

__global__ __launch_bounds__(256) void leconv_mfma(
    const short* __restrict__ Hb,
    const short* __restrict__ Wp1, const short* __restrict__ Wp2, const short* __restrict__ Wp3,
    const float* __restrict__ b1v, const float* __restrict__ b3v,
    const float* __restrict__ deg,
    short* __restrict__ Bb, short* __restrict__ OUTb) {
    const int tid = threadIdx.x;
    const int wave = tid >> 6, lane = tid & 63;
    const int row_base = blockIdx.x * 64 + wave * 16;
    const int r15 = lane & 15, kg = lane >> 4;
    int arow = row_base + r15;
    if (arow >= N_NODES) arow = N_NODES - 1;
    const short* aptr = Hb + (size_t)arow * HID + kg * 8;

    f32x4 acc1[8], acc2[8], acc3[8];
    #pragma unroll
    for (int t = 0; t < 8; t++) {
        acc1[t] = (f32x4)0.f; acc2[t] = (f32x4)0.f; acc3[t] = (f32x4)0.f;
    }
    #pragma unroll
    for (int kb = 0; kb < 4; kb++) {
        short8 av = *(const short8*)(aptr + kb * 32);
        #pragma unroll
        for (int t = 0; t < 8; t++) {
            const int widx = (kb * 8 + t) * 512 + lane * 8;
            short8 w1 = *(const short8*)(Wp1 + widx);
            short8 w2 = *(const short8*)(Wp2 + widx);
            short8 w3 = *(const short8*)(Wp3 + widx);
            acc1[t] = __builtin_amdgcn_mfma_f32_16x16x32_bf16(av, w1, acc1[t], 0, 0, 0);
            acc2[t] = __builtin_amdgcn_mfma_f32_16x16x32_bf16(av, w2, acc2[t], 0, 0, 0);
            acc3[t] = __builtin_amdgcn_mfma_f32_16x16x32_bf16(av, w3, acc3[t], 0, 0, 0);
        }
    }
    int grow[4]; bool ok[4]; float dg[4];
    #pragma unroll
    for (int i = 0; i < 4; i++) {
        grow[i] = row_base + kg * 4 + i;
        ok[i] = grow[i] < N_NODES;
        dg[i] = ok[i] ? deg[grow[i]] : 0.f;
    }
    #pragma unroll
    for (int t = 0; t < 8; t++) {
        const int c = t * 16 + r15;
        const float bb1 = b1v[c], bb3 = b3v[c];
        #pragma unroll
        for (int i = 0; i < 4; i++) {
            if (ok[i]) {
                size_t o = (size_t)grow[i] * HID + c;
                OUTb[o] = bf16_bits(dg[i] * (acc1[t][i] + bb1) + acc3[t][i] + bb3);
                Bb[o] = bf16_bits(acc2[t][i]);
            }
        }
    }
}

// ---------------- pool (mean of bf16 H) + FFN head ----------------

__global__ __launch_bounds__(128) void pool_ffn_kernel(const short* __restrict__ H,
                                                       const int* __restrict__ batch,
                                                       const float* __restrict__ Wf1,
                                                       const float* __restrict__ bf1,
                                                       const float* __restrict__ Wf2,
                                                       const float* __restrict__ bf2,
                                                       float* __restrict__ out) {
    const int g = blockIdx.x;
    const int t = threadIdx.x;  // 0..127

    int lo = 0, hi = N_NODES;
    while (lo < hi) { int mid = (lo + hi) >> 1; if (batch[mid] < g) lo = mid + 1; else hi = mid; }
    const int s = lo;
    hi = N_NODES;
    while (lo < hi) { int mid = (lo + hi) >> 1; if (batch[mid] < g + 1) lo = mid + 1; else hi = mid; }
    const int e = lo;

    float sum = 0.f;
    for (int n = s; n < e; n++) {
        short b = H[(size_t)n * HID + t];
        sum += __bfloat162float(*(__hip_bfloat16*)&b);
    }
    const float cntf = (float)(e - s);
    const float gx = sum / fmaxf(cntf, 1.f);

    __shared__ float lds[HID];
    lds[t] = gx;
    __syncthreads();

    float hsum = bf1[t];
    #pragma unroll 8
    for (int k = 0; k < HID; k++) hsum = fmaf(lds[k], Wf1[k * HID + t], hsum);
    const float hr = fmaxf(hsum, 0.f);

    float p0 = hr * Wf2[t * 2 + 0];
    float p1 = hr * Wf2[t * 2 + 1];
    #pragma unroll
    for (int off = 32; off > 0; off >>= 1) {
        p0 += __shfl_down(p0, off, 64);
        p1 += __shfl_down(p1, off, 64);
    }
    __shared__ float red[4];
    if ((t & 63) == 0) {
        red[(t >> 6) * 2 + 0] = p0;
        red[(t >> 6) * 2 + 1] = p1;
    }
    __syncthreads();
    if (t == 0) {
        out[g * 2 + 0] = red[0] + red[2] + bf2[0];
        out[g * 2 + 1] = red[1] + red[3] + bf2[1];
    }
}

// ---------------- launch ----------------

extern "C" void kernel_launch(void* const* d_in, const int* in_sizes, int n_in,
                              void* d_out, int out_size, void* d_ws, size_t ws_size,
                              hipStream_t stream) {
    (void)in_sizes; (void)n_in; (void)out_size; (void)ws_size;

    const float* x     = (const float*)d_in[0];
    const int*   ei    = (const int*)d_in[1];
    const int*   batch = (const int*)d_in[2];
    const float* W[9] = {
        (const float*)d_in[3],  (const float*)d_in[5],  (const float*)d_in[6],
        (const float*)d_in[8],  (const float*)d_in[10], (const float*)d_in[11],
        (const float*)d_in[13], (const float*)d_in[15], (const float*)d_in[16]};
    const float* b1_0 = (const float*)d_in[4];
    const float* b3_0 = (const float*)d_in[7];
    const float* b1_1 = (const float*)d_in[9];
    const float* b3_1 = (const float*)d_in[12];
    const float* b1_2 = (const float*)d_in[14];
    const float* b3_2 = (const float*)d_in[17];
    const float* Wf1  = (const float*)d_in[18];
    const float* bf1  = (const float*)d_in[19];
    const float* Wf2  = (const float*)d_in[20];
    const float* bf2  = (const float*)d_in[21];
    float* out = (float*)d_out;

    char* ws = (char*)d_ws;
    size_t off = 0;
    auto alloc = [&](size_t bytes) {
        void* p = ws + off;
        off += (bytes + 255) & ~(size_t)255;
        return p;
    };
    short* D0     = (short*)alloc((size_t)N_NODES * HID * 2);  // layer0 D; reused as OUT of gemm2
    short* E0     = (short*)alloc((size_t)N_NODES * HID * 2);  // layer0 E; reused as OUT of gemm1
    short* Bb_A   = (short*)alloc((size_t)N_NODES * HID * 2);
    short* Bb_B   = (short*)alloc((size_t)N_NODES * HID * 2);
    short* Hb     = (short*)alloc((size_t)N_NODES * HID * 2);
    float* degf   = (float*)alloc((size_t)N_NODES * 4);
    int*   rowptr = (int*)alloc((size_t)(N_NODES + 1) * 4);
    int*   cnt    = (int*)alloc((size_t)N_NODES * 4);
    int*   col    = (int*)alloc((size_t)N_EDGES * 4);
    int*   rank   = (int*)alloc((size_t)N_EDGES * 4);
    int*   partial= (int*)alloc((size_t)N_NODES * 4);
    int*   bsum   = (int*)alloc(1024);
    short* P[9];
    for (int m = 0; m < 9; m++) P[m] = (short*)alloc(16384 * 2);

    hipMemsetAsync(cnt, 0, (size_t)N_NODES * 4, stream);

    PackArgs pa;
    for (int m = 0; m < 9; m++) { pa.w[m] = W[m]; pa.o[m] = P[m]; }

    // pre-pack layer-0 weights (needed by phase1 gemm0)
    prepack_kernel<<<PREPACK_BLOCKS, 256, 0, stream>>>(pa);

    // phase 1: gemm0 (from fp32 x) || hist+rank || pack m3..8
    P1Args p1{ x, ei, cnt, rank, P[0], P[1], P[2], b1_0, b3_0, D0, E0, Bb_A, pa };
    phase1_kernel<<<GEMM_GRID + HIST_BLOCKS + PACK67_BLOCKS, 256, 0, stream>>>(p1);

    // scan
    const int NSB = (N_NODES + 1023) / 1024;  // 98
    scan_blocks<<<NSB, 1024, 0, stream>>>(cnt, partial, bsum);
    scan_finalize<<<NSB, 1024, 0, stream>>>(partial, bsum, cnt, rowptr, degf);

    // fill: scatter col (no atomics)
    fill_kernel<<<HIST_BLOCKS, 256, 0, stream>>>(ei, rank, rowptr, col);

    const int gather_grid = (N_NODES * 64 + 255) / 256;  // 25000

    // layer 0 gather: Hb = relu(deg*D0 + E0 - agg(Bb_A))
    gather0_kernel<<<gather_grid, 256, 0, stream>>>(rowptr, col, Bb_A, D0, E0, Hb);
    // layer 1 gemm: E0 <- OUT1, Bb_B
    leconv_mfma<<<GEMM_GRID, 256, 0, stream>>>(Hb, P[3], P[4], P[5], b1_1, b3_1, degf, Bb_B, E0);
    // layer 1 gather
    gatherL_kernel<<<gather_grid, 256, 0, stream>>>(rowptr, col, Bb_B, E0, Hb);
    // layer 2 gemm: D0 <- OUT2, Bb_A
    leconv_mfma<<<GEMM_GRID, 256, 0, stream>>>(Hb, P[6], P[7], P[8], b1_2, b3_2, degf, Bb_A, D0);
    // layer 2 gather
    gatherL_kernel<<<gather_grid, 256, 0, stream>>>(rowptr, col, Bb_A, D0, Hb);

    // pool + FFN
    pool_ffn_kernel<<<N_GRAPHS, 128, 0, stream>>>(Hb, batch, Wf1, bf1, Wf2, bf2, out);
}

// Round 9
// 475.284 us; speedup vs baseline: 1.6366x; 1.1078x over previous
//
#include <hip/hip_runtime.h>
#include <hip/hip_bf16.h>
#include <cstdint>

#define N_NODES 100000
#define N_EDGES 1600000
#define N_GRAPHS 2000
#define IN_DIM 37
#define HID 128

#define GEMM_GRID 1563      // 64-node tiles
#define HIST_BLOCKS 6250    // 1.6M / 256
#define PACK67_BLOCKS 384   // 6*16384/256 (m=3..8)
#define PREPACK_BLOCKS 96   // 3*8192/256  (m=0..2)

typedef __attribute__((ext_vector_type(8))) short short8;
typedef __attribute__((ext_vector_type(4))) float f32x4;

static __device__ __forceinline__ short bf16_bits(float f) {
    __hip_bfloat16 h = __float2bfloat16(f);
    return *reinterpret_cast<short*>(&h);
}
static __device__ __forceinline__ float bf16_lo(uint32_t u) {
    uint32_t v = u << 16;
    return *reinterpret_cast<float*>(&v);
}
static __device__ __forceinline__ float bf16_hi(uint32_t u) {
    uint32_t v = u & 0xffff0000u;
    return *reinterpret_cast<float*>(&v);
}
static __device__ __forceinline__ uint32_t pack_bf16(float lo, float hi) {
    return ((uint32_t)(uint16_t)bf16_bits(hi) << 16) | (uint16_t)bf16_bits(lo);
}

// ---------------- weight pack ----------------

struct PackArgs {
    const float* w[9];
    short* o[9];
};

static __device__ __forceinline__ void pack_one(const PackArgs& pa, int m, int r, int kin) {
    const int i = r & 7, lane = (r >> 3) & 63, t = (r >> 9) & 7, kb = r >> 12;
    const int k = kb * 32 + (lane >> 4) * 8 + i;
    const int c = t * 16 + (lane & 15);
    float v = (k < kin) ? pa.w[m][(size_t)k * HID + c] : 0.f;
    pa.o[m][r] = bf16_bits(v);
}

__global__ __launch_bounds__(256) void prepack_kernel(PackArgs pa) {
    const int idx = blockIdx.x * 256 + threadIdx.x;  // < 24576
    pack_one(pa, idx >> 13, idx & 8191, IN_DIM);
}

// ---------------- layer-0 GEMM from fp32 x (K=64 padded) ----------------
// D0 = bf16(x@W1 + b1), E0 = bf16(x@W3 + b3), Bb = bf16(x@W2)

static __device__ __forceinline__ void gemm0_body(
    int blk, const float* __restrict__ x,
    const short* __restrict__ Wp1, const short* __restrict__ Wp2, const short* __restrict__ Wp3,
    const float* __restrict__ b1v, const float* __restrict__ b3v,
    short* __restrict__ D0, short* __restrict__ E0, short* __restrict__ Bb) {
    const int tid = threadIdx.x;
    const int wave = tid >> 6, lane = tid & 63;
    const int row_base = blk * 64 + wave * 16;
    const int r15 = lane & 15, kg = lane >> 4;
    int arow = row_base + r15;
    if (arow >= N_NODES) arow = N_NODES - 1;
    const float* xr = x + (size_t)arow * IN_DIM;

    f32x4 acc1[8], acc2[8], acc3[8];
    #pragma unroll
    for (int t = 0; t < 8; t++) {
        acc1[t] = (f32x4)0.f; acc2[t] = (f32x4)0.f; acc3[t] = (f32x4)0.f;
    }
    #pragma unroll
    for (int kb = 0; kb < 2; kb++) {
        short8 av;
        #pragma unroll
        for (int i = 0; i < 8; i++) {
            const int k = kb * 32 + kg * 8 + i;
            av[i] = (k < IN_DIM) ? bf16_bits(xr[k]) : (short)0;
        }
        #pragma unroll
        for (int t = 0; t < 8; t++) {
            const int widx = (kb * 8 + t) * 512 + lane * 8;
            short8 w1 = *(const short8*)(Wp1 + widx);
            short8 w2 = *(const short8*)(Wp2 + widx);
            short8 w3 = *(const short8*)(Wp3 + widx);
            acc1[t] = __builtin_amdgcn_mfma_f32_16x16x32_bf16(av, w1, acc1[t], 0, 0, 0);
            acc2[t] = __builtin_amdgcn_mfma_f32_16x16x32_bf16(av, w2, acc2[t], 0, 0, 0);
            acc3[t] = __builtin_amdgcn_mfma_f32_16x16x32_bf16(av, w3, acc3[t], 0, 0, 0);
        }
    }
    int grow[4]; bool ok[4];
    #pragma unroll
    for (int i = 0; i < 4; i++) {
        grow[i] = row_base + kg * 4 + i;
        ok[i] = grow[i] < N_NODES;
    }
    #pragma unroll
    for (int t = 0; t < 8; t++) {
        const int c = t * 16 + r15;
        const float bb1 = b1v[c], bb3 = b3v[c];
        #pragma unroll
        for (int i = 0; i < 4; i++) {
            if (ok[i]) {
                size_t o = (size_t)grow[i] * HID + c;
                D0[o] = bf16_bits(acc1[t][i] + bb1);
                E0[o] = bf16_bits(acc3[t][i] + bb3);
                Bb[o] = bf16_bits(acc2[t][i]);
            }
        }
    }
}

// ---------------- phase 1: gemm0 || hist(+rank, only atomic pass) || pack m3..8 ----------------

struct P1Args {
    const float* x;
    const int* ei;
    int* cnt; int* rank;
    const short* Wp1; const short* Wp2; const short* Wp3;
    const float* b1; const float* b3;
    short* D0; short* E0; short* Bb;
    PackArgs pa;
};

__global__ __launch_bounds__(256) void phase1_kernel(P1Args a) {
    const int b = blockIdx.x;
    if (b < GEMM_GRID) {
        gemm0_body(b, a.x, a.Wp1, a.Wp2, a.Wp3, a.b1, a.b3, a.D0, a.E0, a.Bb);
        return;
    }
    if (b < GEMM_GRID + HIST_BLOCKS) {
        const int e = (b - GEMM_GRID) * 256 + threadIdx.x;
        const int d = a.ei[N_EDGES + e];
        a.rank[e] = atomicAdd(&a.cnt[d], 1);
        return;
    }
    const int idx = (b - GEMM_GRID - HIST_BLOCKS) * 256 + threadIdx.x;  // < 98304
    pack_one(a.pa, 3 + (idx >> 14), idx & 16383, HID);
}

// ---------------- scan: cnt -> rowptr (+degf) ----------------

__global__ __launch_bounds__(1024) void scan_blocks(const int* __restrict__ cnt,
                                                    int* __restrict__ partial,
                                                    int* __restrict__ bsum) {
    __shared__ int ws[16];
    const int tid = threadIdx.x, lane = tid & 63, wv = tid >> 6;
    const int i = blockIdx.x * 1024 + tid;
    int v0 = (i < N_NODES) ? cnt[i] : 0;
    int v = v0;
    #pragma unroll
    for (int off = 1; off < 64; off <<= 1) {
        int n = __shfl_up(v, off, 64);
        if (lane >= off) v += n;
    }
    if (lane == 63) ws[wv] = v;
    __syncthreads();
    int woff = 0, tot = 0;
    #pragma unroll
    for (int w = 0; w < 16; w++) {
        int s = ws[w];
        if (w < wv) woff += s;
        tot += s;
    }
    if (i < N_NODES) partial[i] = woff + v - v0;
    if (tid == 0) bsum[blockIdx.x] = tot;
}

__global__ __launch_bounds__(1024) void scan_finalize(const int* __restrict__ partial,
                                                      const int* __restrict__ bsum,
                                                      const int* __restrict__ cnt,
                                                      int* __restrict__ rowptr,
                                                      float* __restrict__ degf) {
    __shared__ int off_s;
    const int tid = threadIdx.x, b = blockIdx.x;
    if (tid < 64) {
        int acc = 0;
        for (int j = tid; j < b; j += 64) acc += bsum[j];
        #pragma unroll
        for (int off = 32; off; off >>= 1) acc += __shfl_down(acc, off, 64);
        if (tid == 0) off_s = acc;
    }
    __syncthreads();
    const int i = b * 1024 + tid;
    if (i < N_NODES) {
        rowptr[i] = off_s + partial[i];
        degf[i] = (float)cnt[i];
    }
    if (b == 0 && tid == 0) rowptr[N_NODES] = N_EDGES;
}

// ---------------- fill: scatter col (no atomics) ----------------

__global__ __launch_bounds__(256) void fill_kernel(const int* __restrict__ ei,
                                                   const int* __restrict__ rank,
                                                   const int* __restrict__ rowptr,
                                                   int* __restrict__ col) {
    const int e = blockIdx.x * 256 + threadIdx.x;
    const int s = ei[e];
    const int d = ei[N_EDGES + e];
    col[rowptr[d] + rank[e]] = s;
}

// ---------------- gather core: 4 edges/wave-iter, 16B/lane, col prefetch+shuffle ----------------
// acc[j] accumulates col (l16*8 + j) over all edges of the node; valid in ALL lanes after reduce.

static __device__ __forceinline__ void agg_edges4(const int* __restrict__ col, int s, int e,
                                                  const short* __restrict__ Bb,
                                                  int lane, int grp, int l16, float* acc) {
    for (int base = s; base < e; base += 64) {
        const int cnt = min(64, e - base);
        const int ci = base + lane;
        const int cv = col[(ci < e) ? ci : (e - 1)];
        for (int t = 0; t < cnt; t += 4) {
            const int idx = t + grp;
            const bool on = idx < cnt;
            const float w = on ? 1.f : 0.f;
            const int c = __shfl(cv, on ? idx : 0, 64);
            const uint4 u = *(const uint4*)(Bb + (size_t)c * HID + l16 * 8);
            acc[0] = fmaf(w, bf16_lo(u.x), acc[0]);
            acc[1] = fmaf(w, bf16_hi(u.x), acc[1]);
            acc[2] = fmaf(w, bf16_lo(u.y), acc[2]);
            acc[3] = fmaf(w, bf16_hi(u.y), acc[3]);
            acc[4] = fmaf(w, bf16_lo(u.z), acc[4]);
            acc[5] = fmaf(w, bf16_hi(u.z), acc[5]);
            acc[6] = fmaf(w, bf16_lo(u.w), acc[6]);
            acc[7] = fmaf(w, bf16_hi(u.w), acc[7]);
        }
    }
    #pragma unroll
    for (int j = 0; j < 8; j++) {
        acc[j] += __shfl_xor(acc[j], 16, 64);
        acc[j] += __shfl_xor(acc[j], 32, 64);
    }
}

// layer-0 gather: Hb = bf16(relu(deg*D0 - agg + E0)), deg from rowptr
__global__ __launch_bounds__(256) void gather0_kernel(const int* __restrict__ rowptr,
                                                      const int* __restrict__ col,
                                                      const short* __restrict__ Bb,
                                                      const short* __restrict__ D0,
                                                      const short* __restrict__ E0,
                                                      short* __restrict__ Hb) {
    const int wid = (blockIdx.x * 256 + threadIdx.x) >> 6;
    if (wid >= N_NODES) return;
    const int lane = threadIdx.x & 63, grp = lane >> 4, l16 = lane & 15;
    const int s = rowptr[wid], e = rowptr[wid + 1];
    float acc[8] = {0.f, 0.f, 0.f, 0.f, 0.f, 0.f, 0.f, 0.f};
    agg_edges4(col, s, e, Bb, lane, grp, l16, acc);
    if (grp == 0) {
        const float dg = (float)(e - s);
        const uint4 ud = *(const uint4*)(D0 + (size_t)wid * HID + l16 * 8);
        const uint4 ue = *(const uint4*)(E0 + (size_t)wid * HID + l16 * 8);
        uint4 r;
        r.x = pack_bf16(fmaxf(fmaf(dg, bf16_lo(ud.x), bf16_lo(ue.x)) - acc[0], 0.f),
                        fmaxf(fmaf(dg, bf16_hi(ud.x), bf16_hi(ue.x)) - acc[1], 0.f));
        r.y = pack_bf16(fmaxf(fmaf(dg, bf16_lo(ud.y), bf16_lo(ue.y)) - acc[2], 0.f),
                        fmaxf(fmaf(dg, bf16_hi(ud.y), bf16_hi(ue.y)) - acc[3], 0.f));
        r.z = pack_bf16(fmaxf(fmaf(dg, bf16_lo(ud.z), bf16_lo(ue.z)) - acc[4], 0.f),
                        fmaxf(fmaf(dg, bf16_hi(ud.z), bf16_hi(ue.z)) - acc[5], 0.f));
        r.w = pack_bf16(fmaxf(fmaf(dg, bf16_lo(ud.w), bf16_lo(ue.w)) - acc[6], 0.f),
                        fmaxf(fmaf(dg, bf16_hi(ud.w), bf16_hi(ue.w)) - acc[7], 0.f));
        *(uint4*)(Hb + (size_t)wid * HID + l16 * 8) = r;
    }
}

// layers 1/2 gather: Hb = bf16(relu(OUT - agg)), OUT bf16 (deg applied in gemm)
__global__ __launch_bounds__(256) void gatherL_kernel(const int* __restrict__ rowptr,
                                                      const int* __restrict__ col,
                                                      const short* __restrict__ Bb,
                                                      const short* __restrict__ OUTb,
                                                      short* __restrict__ Hb) {
    const int wid = (blockIdx.x * 256 + threadIdx.x) >> 6;
    if (wid >= N_NODES) return;
    const int lane = threadIdx.x & 63, grp = lane >> 4, l16 = lane & 15;
    const int s = rowptr[wid], e = rowptr[wid + 1];
    float acc[8] = {0.f, 0.f, 0.f, 0.f, 0.f, 0.f, 0.f, 0.f};
    agg_edges4(col, s, e, Bb, lane, grp, l16, acc);
    if (grp == 0) {
        const uint4 uo = *(const uint4*)(OUTb + (size_t)wid * HID + l16 * 8);
        uint4 r;
        r.x = pack_bf16(fmaxf(bf16_lo(uo.x) - acc[0], 0.f), fmaxf(bf16_hi(uo.x) - acc[1], 0.f));
        r.y = pack_bf16(fmaxf(bf16_lo(uo.y) - acc[2], 0.f), fmaxf(bf16_hi(uo.y) - acc[3], 0.f));
        r.z = pack_bf16(fmaxf(bf16_lo(uo.z) - acc[4], 0.f), fmaxf(bf16_hi(uo.z) - acc[5], 0.f));
        r.w = pack_bf16(fmaxf(bf16_lo(uo.w) - acc[6], 0.f), fmaxf(bf16_hi(uo.w) - acc[7], 0.f));
        *(uint4*)(Hb + (size_t)wid * HID + l16 * 8) = r;
    }
}

// ---------------- layers 1/2 GEMM: OUT = bf16(deg*(h@W1+b1)+h@W3+b3), Bb = bf16(h@W2) ----------------

__global__ __launch_bounds__(256) void leconv_mfma(
    const short* __restrict__ Hb,
    const short* __restrict__ Wp1, const short* __restrict__ Wp2, const short* __restrict__ Wp3,
    const float* __restrict__ b1v, const float* __restrict__ b3v,
    const float* __restrict__ deg,
    short* __restrict__ Bb, short* __restrict__ OUTb) {
    const int tid = threadIdx.x;
    const int wave = tid >> 6, lane = tid & 63;
    const int row_base = blockIdx.x * 64 + wave * 16;
    const int r15 = lane & 15, kg = lane >> 4;
    int arow = row_base + r15;
    if (arow >= N_NODES) arow = N_NODES - 1;
    const short* aptr = Hb + (size_t)arow * HID + kg * 8;

    f32x4 acc1[8], acc2[8], acc3[8];
    #pragma unroll
    for (int t = 0; t < 8; t++) {
        acc1[t] = (f32x4)0.f; acc2[t] = (f32x4)0.f; acc3[t] = (f32x4)0.f;
    }
    #pragma unroll
    for (int kb = 0; kb < 4; kb++) {
        short8 av = *(const short8*)(aptr + kb * 32);
        #pragma unroll
        for (int t = 0; t < 8; t++) {
            const int widx = (kb * 8 + t) * 512 + lane * 8;
            short8 w1 = *(const short8*)(Wp1 + widx);
            short8 w2 = *(const short8*)(Wp2 + widx);
            short8 w3 = *(const short8*)(Wp3 + widx);
            acc1[t] = __builtin_amdgcn_mfma_f32_16x16x32_bf16(av, w1, acc1[t], 0, 0, 0);
            acc2[t] = __builtin_amdgcn_mfma_f32_16x16x32_bf16(av, w2, acc2[t], 0, 0, 0);
            acc3[t] = __builtin_amdgcn_mfma_f32_16x16x32_bf16(av, w3, acc3[t], 0, 0, 0);
        }
    }
    int grow[4]; bool ok[4]; float dg[4];
    #pragma unroll
    for (int i = 0; i < 4; i++) {
        grow[i] = row_base + kg * 4 + i;
        ok[i] = grow[i] < N_NODES;
        dg[i] = ok[i] ? deg[grow[i]] : 0.f;
    }
    #pragma unroll
    for (int t = 0; t < 8; t++) {
        const int c = t * 16 + r15;
        const float bb1 = b1v[c], bb3 = b3v[c];
        #pragma unroll
        for (int i = 0; i < 4; i++) {
            if (ok[i]) {
                size_t o = (size_t)grow[i] * HID + c;
                OUTb[o] = bf16_bits(dg[i] * (acc1[t][i] + bb1) + acc3[t][i] + bb3);
                Bb[o] = bf16_bits(acc2[t][i]);
            }
        }
    }
}

// ---------------- pool (mean of bf16 H) + FFN head ----------------

__global__ __launch_bounds__(128) void pool_ffn_kernel(const short* __restrict__ H,
                                                       const int* __restrict__ batch,
                                                       const float* __restrict__ Wf1,
                                                       const float* __restrict__ bf1,
                                                       const float* __restrict__ Wf2,
                                                       const float* __restrict__ bf2,
                                                       float* __restrict__ out) {
    const int g = blockIdx.x;
    const int t = threadIdx.x;  // 0..127

    int lo = 0, hi = N_NODES;
    while (lo < hi) { int mid = (lo + hi) >> 1; if (batch[mid] < g) lo = mid + 1; else hi = mid; }
    const int s = lo;
    hi = N_NODES;
    while (lo < hi) { int mid = (lo + hi) >> 1; if (batch[mid] < g + 1) lo = mid + 1; else hi = mid; }
    const int e = lo;

    float sum = 0.f;
    for (int n = s; n < e; n++) {
        short b = H[(size_t)n * HID + t];
        sum += __bfloat162float(*(__hip_bfloat16*)&b);
    }
    const float cntf = (float)(e - s);
    const float gx = sum / fmaxf(cntf, 1.f);

    __shared__ float lds[HID];
    lds[t] = gx;
    __syncthreads();

    float hsum = bf1[t];
    #pragma unroll 8
    for (int k = 0; k < HID; k++) hsum = fmaf(lds[k], Wf1[k * HID + t], hsum);
    const float hr = fmaxf(hsum, 0.f);

    float p0 = hr * Wf2[t * 2 + 0];
    float p1 = hr * Wf2[t * 2 + 1];
    #pragma unroll
    for (int off = 32; off > 0; off >>= 1) {
        p0 += __shfl_down(p0, off, 64);
        p1 += __shfl_down(p1, off, 64);
    }
    __shared__ float red[4];
    if ((t & 63) == 0) {
        red[(t >> 6) * 2 + 0] = p0;
        red[(t >> 6) * 2 + 1] = p1;
    }
    __syncthreads();
    if (t == 0) {
        out[g * 2 + 0] = red[0] + red[2] + bf2[0];
        out[g * 2 + 1] = red[1] + red[3] + bf2[1];
    }
}

// ---------------- launch ----------------

extern "C" void kernel_launch(void* const* d_in, const int* in_sizes, int n_in,
                              void* d_out, int out_size, void* d_ws, size_t ws_size,
                              hipStream_t stream) {
    (void)in_sizes; (void)n_in; (void)out_size; (void)ws_size;

    const float* x     = (const float*)d_in[0];
    const int*   ei    = (const int*)d_in[1];
    const int*   batch = (const int*)d_in[2];
    const float* W[9] = {
        (const float*)d_in[3],  (const float*)d_in[5],  (const float*)d_in[6],
        (const float*)d_in[8],  (const float*)d_in[10], (const float*)d_in[11],
        (const float*)d_in[13], (const float*)d_in[15], (const float*)d_in[16]};
    const float* b1_0 = (const float*)d_in[4];
    const float* b3_0 = (const float*)d_in[7];
    const float* b1_1 = (const float*)d_in[9];
    const float* b3_1 = (const float*)d_in[12];
    const float* b1_2 = (const float*)d_in[14];
    const float* b3_2 = (const float*)d_in[17];
    const float* Wf1  = (const float*)d_in[18];
    const float* bf1  = (const float*)d_in[19];
    const float* Wf2  = (const float*)d_in[20];
    const float* bf2  = (const float*)d_in[21];
    float* out = (float*)d_out;

    char* ws = (char*)d_ws;
    size_t off = 0;
    auto alloc = [&](size_t bytes) {
        void* p = ws + off;
        off += (bytes + 255) & ~(size_t)255;
        return p;
    };
    short* D0     = (short*)alloc((size_t)N_NODES * HID * 2);  // layer0 D; reused as OUT of gemm2
    short* E0     = (short*)alloc((size_t)N_NODES * HID * 2);  // layer0 E; reused as OUT of gemm1
    short* Bb_A   = (short*)alloc((size_t)N_NODES * HID * 2);
    short* Bb_B   = (short*)alloc((size_t)N_NODES * HID * 2);
    short* Hb     = (short*)alloc((size_t)N_NODES * HID * 2);
    float* degf   = (float*)alloc((size_t)N_NODES * 4);
    int*   rowptr = (int*)alloc((size_t)(N_NODES + 1) * 4);
    int*   cnt    = (int*)alloc((size_t)N_NODES * 4);
    int*   col    = (int*)alloc((size_t)N_EDGES * 4);
    int*   rank   = (int*)alloc((size_t)N_EDGES * 4);
    int*   partial= (int*)alloc((size_t)N_NODES * 4);
    int*   bsum   = (int*)alloc(1024);
    short* P[9];
    for (int m = 0; m < 9; m++) P[m] = (short*)alloc(16384 * 2);

    hipMemsetAsync(cnt, 0, (size_t)N_NODES * 4, stream);

    PackArgs pa;
    for (int m = 0; m < 9; m++) { pa.w[m] = W[m]; pa.o[m] = P[m]; }

    // pre-pack layer-0 weights (needed by phase1 gemm0)
    prepack_kernel<<<PREPACK_BLOCKS, 256, 0, stream>>>(pa);

    // phase 1: gemm0 (from fp32 x) || hist+rank || pack m3..8
    P1Args p1{ x, ei, cnt, rank, P[0], P[1], P[2], b1_0, b3_0, D0, E0, Bb_A, pa };
    phase1_kernel<<<GEMM_GRID + HIST_BLOCKS + PACK67_BLOCKS, 256, 0, stream>>>(p1);

    // scan
    const int NSB = (N_NODES + 1023) / 1024;  // 98
    scan_blocks<<<NSB, 1024, 0, stream>>>(cnt, partial, bsum);
    scan_finalize<<<NSB, 1024, 0, stream>>>(partial, bsum, cnt, rowptr, degf);

    // fill: scatter col (no atomics)
    fill_kernel<<<HIST_BLOCKS, 256, 0, stream>>>(ei, rank, rowptr, col);

    const int gather_grid = (N_NODES * 64 + 255) / 256;  // 25000

    // layer 0 gather: Hb = relu(deg*D0 + E0 - agg(Bb_A))
    gather0_kernel<<<gather_grid, 256, 0, stream>>>(rowptr, col, Bb_A, D0, E0, Hb);
    // layer 1 gemm: E0 <- OUT1, Bb_B
    leconv_mfma<<<GEMM_GRID, 256, 0, stream>>>(Hb, P[3], P[4], P[5], b1_1, b3_1, degf, Bb_B, E0);
    // layer 1 gather
    gatherL_kernel<<<gather_grid, 256, 0, stream>>>(rowptr, col, Bb_B, E0, Hb);
    // layer 2 gemm: D0 <- OUT2, Bb_A
    leconv_mfma<<<GEMM_GRID, 256, 0, stream>>>(Hb, P[6], P[7], P[8], b1_2, b3_2, degf, Bb_A, D0);
    // layer 2 gather
    gatherL_kernel<<<gather_grid, 256, 0, stream>>>(rowptr, col, Bb_A, D0, Hb);

    // pool + FFN
    pool_ffn_kernel<<<N_GRAPHS, 128, 0, stream>>>(Hb, batch, Wf1, bf1, Wf2, bf2, out);
}